// Round 1
// baseline (810.216 us; speedup 1.0000x reference)
//
#include <hip/hip_runtime.h>
#include <hip/hip_bf16.h>
#include <math.h>

#define T_TOK 8192
#define DM 1024
#define DF 4096
#define NE 8
#define MAXT 72    // max 256-row tiles: 64 full + 7 partials + slack

typedef __attribute__((ext_vector_type(4))) float  f32x4;
typedef __attribute__((ext_vector_type(8))) short  s16x8;
typedef __attribute__((ext_vector_type(8))) unsigned short u16x8;

__device__ __forceinline__ unsigned short f2bf(float f) {
    unsigned int u = __builtin_bit_cast(unsigned int, f);
    u = (u + 0x7FFFu + ((u >> 16) & 1u)) >> 16;
    return (unsigned short)u;
}

#define GLDS16(gptr, lptr)                                                         \
    __builtin_amdgcn_global_load_lds(                                              \
        (const __attribute__((address_space(1))) void*)(gptr),                     \
        (__attribute__((address_space(3))) void*)(lptr), 16, 0, 0)

#define BAR() asm volatile("s_barrier" ::: "memory")

template<int W>
__device__ __forceinline__ void waitvm() {
    if constexpr (W == 8)      asm volatile("s_waitcnt vmcnt(8)" ::: "memory");
    else                       asm volatile("s_waitcnt vmcnt(0)" ::: "memory");
}

// ---------------- Routing ----------------
__global__ __launch_bounds__(256) void route_kernel(
    const float* __restrict__ x, const float* __restrict__ Wg,
    int* __restrict__ counts, int* __restrict__ lists, float* __restrict__ pw)
{
    int tok  = (int)((blockIdx.x * blockDim.x + threadIdx.x) >> 6);
    int lane = threadIdx.x & 63;
    if (tok >= T_TOK) return;

    const float* xr = x + (size_t)tok * DM;
    float acc[NE];
#pragma unroll
    for (int e = 0; e < NE; ++e) acc[e] = 0.f;

    for (int i = lane; i < DM; i += 64) {
        float xv = xr[i];
        const float* wr = Wg + (size_t)i * NE;
#pragma unroll
        for (int e = 0; e < NE; ++e) acc[e] += xv * wr[e];
    }
#pragma unroll
    for (int e = 0; e < NE; ++e) {
#pragma unroll
        for (int off = 32; off > 0; off >>= 1)
            acc[e] += __shfl_xor(acc[e], off, 64);
    }

    if (lane == 0) {
        int i0 = 0; float v0 = acc[0];
#pragma unroll
        for (int e = 1; e < NE; ++e) if (acc[e] > v0) { v0 = acc[e]; i0 = e; }
        int i1 = -1; float v1 = -INFINITY;
#pragma unroll
        for (int e = 0; e < NE; ++e) if (e != i0 && acc[e] > v1) { v1 = acc[e]; i1 = e; }
        float e1 = __expf(v1 - v0);
        float s  = 1.f + e1;
        int p0 = tok * 2, p1 = tok * 2 + 1;
        pw[p0] = 1.f / s;
        pw[p1] = e1 / s;
        int pos0 = atomicAdd(&counts[i0], 1);
        lists[i0 * T_TOK + pos0] = p0;
        int pos1 = atomicAdd(&counts[i1], 1);
        lists[i1 * T_TOK + pos1] = p1;
    }
}

// offsets + 256-row tile table (e<<20 | slot0) + live tile count
__global__ void offsets_kernel(const int* __restrict__ counts, int* __restrict__ offsets,
                               unsigned* __restrict__ table, int* __restrict__ ntp)
{
    if (threadIdx.x == 0) {
        int s = 0, ti = 0;
        for (int e = 0; e < NE; ++e) {
            offsets[e] = s;
            int cnt = counts[e];
            for (int t0 = 0; t0 < cnt; t0 += 256)
                table[ti++] = ((unsigned)e << 20) | (unsigned)t0;
            s += cnt;
        }
        ntp[0] = ti;
        for (; ti < MAXT; ++ti) table[ti] = 0xFFFFFFFFu;
    }
}

// ---------------- x fp32 -> bf16 ----------------
__global__ __launch_bounds__(256) void conv_x_kernel(
    const float* __restrict__ x, unsigned short* __restrict__ xb)
{
    size_t i = ((size_t)blockIdx.x * 256 + threadIdx.x) * 8;
    float4 v0 = *reinterpret_cast<const float4*>(x + i);
    float4 v1 = *reinterpret_cast<const float4*>(x + i + 4);
    u16x8 o;
    o[0] = f2bf(v0.x); o[1] = f2bf(v0.y); o[2] = f2bf(v0.z); o[3] = f2bf(v0.w);
    o[4] = f2bf(v1.x); o[5] = f2bf(v1.y); o[6] = f2bf(v1.z); o[7] = f2bf(v1.w);
    *reinterpret_cast<u16x8*>(xb + i) = o;
}

// ---------------- W [E][K][N] fp32 -> Wt [E][N][K] bf16 (16B/lane both sides) --------
template<int K, int N>
__global__ __launch_bounds__(256) void transpose_conv_kernel(
    const float* __restrict__ W, unsigned short* __restrict__ Wt)
{
    int e  = blockIdx.z;
    int k0 = blockIdx.x * 64;
    int n0 = blockIdx.y * 64;
    const float* We = W + (size_t)e * K * N;
    unsigned short* Wte = Wt + (size_t)e * K * N;

    __shared__ unsigned short t[64][73];
    int c4 = (threadIdx.x & 15) * 4;
    int r  = threadIdx.x >> 4;              // 0..15
#pragma unroll
    for (int i = 0; i < 4; ++i) {
        int rr = r + i * 16;
        float4 v = *reinterpret_cast<const float4*>(We + (size_t)(k0 + rr) * N + n0 + c4);
        t[rr][c4 + 0] = f2bf(v.x); t[rr][c4 + 1] = f2bf(v.y);
        t[rr][c4 + 2] = f2bf(v.z); t[rr][c4 + 3] = f2bf(v.w);
    }
    __syncthreads();
    int kc = (threadIdx.x & 7) * 8;
    int rn = threadIdx.x >> 3;              // 0..31
#pragma unroll
    for (int i = 0; i < 2; ++i) {
        int nn = rn + i * 32;
        u16x8 o;
#pragma unroll
        for (int j = 0; j < 8; ++j) o[j] = t[kc + j][nn];
        *reinterpret_cast<u16x8*>(Wte + (size_t)(n0 + nn) * K + k0 + kc) = o;
    }
}

// ---------------- deep-pipeline grouped GEMM ----------------
// BM=256, BN=256, BK=64, 512 thr, 8 waves (2M x 4N), per-wave 128x64, acc[8][4].
// LDS 128 KB: A dbuf 2x32K + B dbuf 2x32K -> 1 block/CU, 2 waves/SIMD.
// Pipeline: all 8 stage loads for K-tile t+2 issued right after the barrier that
// retires tile t's reads; boundary wait is counted vmcnt(8) (waits only for tile
// t+1, which has a full 64-MFMA tile of latency cover). 4 phases per K-tile:
// {ds_read subtile; setprio(1); 16 MFMA; setprio(0); s_barrier}.
// Swizzle (128B rows, 8x16B slots): store slot (t&7)^((t>>3)&7), read slot
// (kh*4+l4)^(l15&7) -> max 2-way (free).
template<int N, int K, int SPLITK, bool IS_G1>
__global__ __launch_bounds__(512, 2) void moe_gemm8(
    const unsigned short* __restrict__ A,
    const unsigned short* __restrict__ Wt,
    const int* __restrict__ counts, const int* __restrict__ offsets,
    const int* __restrict__ lists, const unsigned* __restrict__ table,
    const int* __restrict__ ntp, const float* __restrict__ pw,
    unsigned short* __restrict__ Hout, float* __restrict__ Oout)
{
    constexpr int NT  = N / 256;
    constexpr int PAN = NT * SPLITK;
    constexpr int KS  = K / SPLITK;
    constexpr int NKT = KS / 64;
    static_assert(NKT >= 2, "pipeline depth");

    __shared__ __attribute__((aligned(16))) char lds[131072];
    // A slot s: lds + s*32768 (256 rows x 128B); B slot s: lds + 65536 + s*32768

    int ntl  = ntp[0];
    int live = ntl * PAN;
    int orig = blockIdx.x;
    if (orig >= live) return;
    int q = live >> 3, r = live & 7;
    int xq = orig & 7, ib = orig >> 3;
    int work = (xq < r ? xq * (q + 1) : r * (q + 1) + (xq - r) * q) + ib;
    int rt    = work / PAN;                 // rt-major: neighbors share A-tile
    int panel = work - rt * PAN;
    int nt    = (SPLITK == 2) ? (panel >> 1) : panel;
    int sk    = (SPLITK == 2) ? (panel & 1) : 0;
    int koff  = sk * KS;

    unsigned te = table[rt];
    int e     = (int)(te >> 20);
    int slot0 = (int)(te & 0xFFFFFu);
    int cnt   = counts[e];
    int off   = offsets[e];
    int ntile = nt * 256;

    int tid  = threadIdx.x;
    int lane = tid & 63;
    int wid  = tid >> 6;
    int wm = wid >> 2;                  // 0..1  (128-row half)
    int wn = wid & 3;                   // 0..3  (64-col quarter)
    int l15 = lane & 15, l4 = lane >> 4;

    const unsigned short* Be = Wt + (size_t)e * N * K;

    // ---- staging offsets (elements). store-side swizzle: slot = (t&7)^((t>>3)&7)
    int ssw = ((tid & 7) ^ ((tid >> 3) & 7)) * 8;
    int r0  = tid >> 3;                 // 0..63 (row within 64-row instr group)
    unsigned aOff0, aOff1, aOff2, aOff3;
    {
#pragma unroll
        for (int u = 0; u < 4; ++u) {
            int sl = slot0 + u * 64 + r0;
            unsigned grow;
            if (IS_G1) grow = (sl < cnt) ? (unsigned)(lists[e * T_TOK + sl] >> 1) : 0u;
            else       grow = (unsigned)(off + ((sl < cnt) ? sl : slot0));
            unsigned v = grow * (unsigned)K + (unsigned)(koff + ssw);
            if (u == 0) aOff0 = v; else if (u == 1) aOff1 = v;
            else if (u == 2) aOff2 = v; else aOff3 = v;
        }
    }
    unsigned bOff0 = (unsigned)(ntile + 0   + r0) * (unsigned)K + (unsigned)(koff + ssw);
    unsigned bOff1 = (unsigned)(ntile + 64  + r0) * (unsigned)K + (unsigned)(koff + ssw);
    unsigned bOff2 = (unsigned)(ntile + 128 + r0) * (unsigned)K + (unsigned)(koff + ssw);
    unsigned bOff3 = (unsigned)(ntile + 192 + r0) * (unsigned)K + (unsigned)(koff + ssw);

    auto stage = [&](int s, int kt) {
        int ko = kt * 64;
        char* dA = lds + s * 32768 + tid * 16;
        char* dB = lds + 65536 + s * 32768 + tid * 16;
        GLDS16(A + aOff0 + ko, dA);
        GLDS16(A + aOff1 + ko, dA + 8192);
        GLDS16(A + aOff2 + ko, dA + 16384);
        GLDS16(A + aOff3 + ko, dA + 24576);
        GLDS16(Be + bOff0 + ko, dB);
        GLDS16(Be + bOff1 + ko, dB + 8192);
        GLDS16(Be + bOff2 + ko, dB + 16384);
        GLDS16(Be + bOff3 + ko, dB + 24576);
    };

    // ---- fragment read bases (swizzled; row stride 128B, kh flips slot bit2 = ^64)
    int swz  = (l4 ^ (l15 & 7)) * 16;
    int aRdB = (wm * 128 + l15) * 128 + swz;
    int bRdB = (wn * 64  + l15) * 128 + swz;

    f32x4 acc[8][4];
#pragma unroll
    for (int m = 0; m < 8; ++m)
#pragma unroll
        for (int n = 0; n < 4; ++n) acc[m][n] = (f32x4){0.f, 0.f, 0.f, 0.f};

    // ---- one K-tile = 4 phases (kh x mh). Ends with a barrier (buffer retired).
    auto tilestep = [&](int s) {
        const char* Ab = lds + s * 32768;
        const char* Bb = lds + 65536 + s * 32768;
#pragma unroll
        for (int kh = 0; kh < 2; ++kh) {
            const int khx = kh * 64;
            s16x8 bf[4];
#pragma unroll
            for (int n = 0; n < 4; ++n)
                bf[n] = *reinterpret_cast<const s16x8*>(Bb + ((bRdB + n * 2048) ^ khx));
#pragma unroll
            for (int mh = 0; mh < 2; ++mh) {
                s16x8 af[4];
#pragma unroll
                for (int m = 0; m < 4; ++m)
                    af[m] = *reinterpret_cast<const s16x8*>(Ab + ((aRdB + (mh * 4 + m) * 2048) ^ khx));
                __builtin_amdgcn_s_setprio(1);
#pragma unroll
                for (int n = 0; n < 4; ++n)
#pragma unroll
                    for (int m = 0; m < 4; ++m)
                        acc[mh * 4 + m][n] = __builtin_amdgcn_mfma_f32_16x16x32_bf16(
                            af[m], bf[n], acc[mh * 4 + m][n], 0, 0, 0);
                __builtin_amdgcn_s_setprio(0);
                BAR();
            }
        }
    };

    // ---- pipeline ----
    stage(0, 0);
    stage(1, 1);
    waitvm<8>();            // tile 0 resident
    BAR();
    for (int kt = 0; kt < NKT; ++kt) {
        tilestep(kt & 1);   // trailing BAR: all waves done reading buf kt&1
        if (kt + 2 < NKT) {
            stage(kt & 1, kt + 2);   // refill just-freed buffer
            waitvm<8>();             // tile kt+1 resident (full tile of cover)
        } else {
            waitvm<0>();             // epilogue drain (loads long in flight)
        }
        BAR();
    }

    // ---- epilogue: C/D col = lane&15, row = (lane>>4)*4 + rr ----
#pragma unroll
    for (int m = 0; m < 8; ++m) {
        int trow = wm * 128 + m * 16 + l4 * 4;
#pragma unroll
        for (int rr = 0; rr < 4; ++rr) {
            int slot = slot0 + trow + rr;
            if (slot >= cnt) continue;
            if (IS_G1) {
                unsigned short* hr = Hout + (size_t)(off + slot) * N;
#pragma unroll
                for (int n = 0; n < 4; ++n) {
                    int col = ntile + wn * 64 + n * 16 + l15;
                    float v = acc[m][n][rr];
                    float s = v / (1.f + __expf(-v));
                    hr[col] = f2bf(s);
                }
            } else {
                int p = lists[e * T_TOK + slot];
                float w = pw[p];
                float* orow = Oout + (size_t)(p >> 1) * DM;
#pragma unroll
                for (int n = 0; n < 4; ++n) {
                    int col = ntile + wn * 64 + n * 16 + l15;
                    atomicAdd(orow + col, w * acc[m][n][rr]);
                }
            }
        }
    }
}

// ================= fallback (round-1 validated fp32 path) =================
#define BMF 16
#define BFF 256
__global__ __launch_bounds__(256) void expert_gemm_f32(
    const float* __restrict__ x, const float* __restrict__ W1, const float* __restrict__ W2,
    const int* __restrict__ counts, const int* __restrict__ lists, const float* __restrict__ pw,
    float* __restrict__ out)
{
    int e    = blockIdx.y;
    int tile = blockIdx.x;
    int cnt  = counts[e];
    int start = tile * BMF;
    if (start >= cnt) return;

    __shared__ float xs[BMF][DM];
    __shared__ float hs[BMF][BFF];
    __shared__ int   toks[BMF];
    __shared__ float wgt[BMF];

    int tid = threadIdx.x;
    int nm  = cnt - start; if (nm > BMF) nm = BMF;

    if (tid < BMF) {
        if (tid < nm) {
            int p = lists[e * T_TOK + start + tid];
            toks[tid] = p >> 1;
            wgt[tid]  = pw[p];
        } else { toks[tid] = -1; wgt[tid] = 0.f; }
    }
    __syncthreads();
    for (int m = 0; m < BMF; ++m) {
        int t = toks[m];
        const float* xr = (t >= 0) ? (x + (size_t)t * DM) : nullptr;
        for (int i = tid; i < DM; i += 256) xs[m][i] = (t >= 0) ? xr[i] : 0.f;
    }
    __syncthreads();

    const float* W1e = W1 + (size_t)e * DM * DF;
    const float* W2e = W2 + (size_t)e * DF * DM;
    float acc[BMF][4];
#pragma unroll
    for (int m = 0; m < BMF; ++m)
#pragma unroll
        for (int c = 0; c < 4; ++c) acc[m][c] = 0.f;

    for (int fc = 0; fc < DF; fc += BFF) {
        float hacc[BMF];
#pragma unroll
        for (int m = 0; m < BMF; ++m) hacc[m] = 0.f;
        const float* w1col = W1e + fc + tid;
#pragma unroll 4
        for (int i = 0; i < DM; ++i) {
            float w1v = w1col[(size_t)i * DF];
#pragma unroll
            for (int m = 0; m < BMF; ++m) hacc[m] += xs[m][i] * w1v;
        }
        __syncthreads();
#pragma unroll
        for (int m = 0; m < BMF; ++m) {
            float v = hacc[m];
            hs[m][tid] = v / (1.f + __expf(-v));
        }
        __syncthreads();
        const float* w2base = W2e + (size_t)fc * DM + tid * 4;
        for (int f = 0; f < BFF; ++f) {
            float4 w2v = *reinterpret_cast<const float4*>(w2base + (size_t)f * DM);
#pragma unroll
            for (int m = 0; m < BMF; ++m) {
                float h = hs[m][f];
                acc[m][0] += h * w2v.x; acc[m][1] += h * w2v.y;
                acc[m][2] += h * w2v.z; acc[m][3] += h * w2v.w;
            }
        }
        __syncthreads();
    }
    int c0 = tid * 4;
#pragma unroll
    for (int m = 0; m < BMF; ++m) {
        int t = toks[m];
        if (t < 0) continue;
        float w = wgt[m];
        float* op = out + (size_t)t * DM + c0;
        atomicAdd(op + 0, w * acc[m][0]);
        atomicAdd(op + 1, w * acc[m][1]);
        atomicAdd(op + 2, w * acc[m][2]);
        atomicAdd(op + 3, w * acc[m][3]);
    }
}

// ================= launch =================
extern "C" void kernel_launch(void* const* d_in, const int* in_sizes, int n_in,
                              void* d_out, int out_size, void* d_ws, size_t ws_size,
                              hipStream_t stream)
{
    const float* x  = (const float*)d_in[0];
    const float* Wg = (const float*)d_in[1];
    const float* W1 = (const float*)d_in[2];
    const float* W2 = (const float*)d_in[3];
    float* out = (float*)d_out;

    char* ws = (char*)d_ws;
    int*      counts  = (int*)(ws + 0);
    int*      offsets = (int*)(ws + 64);
    int*      ntp     = (int*)(ws + 128);
    unsigned* table   = (unsigned*)(ws + 256);        // 72*4 = 288 B
    int*      lists   = (int*)(ws + 2048);            // 256 KB
    float*    pw      = (float*)(ws + 2048 + 262144); // 64 KB

    const size_t o_xb  = 524288;
    const size_t sz_xb = (size_t)T_TOK * DM * 2;              // 16 MB
    const size_t o_w1t = o_xb + sz_xb;
    const size_t sz_w  = (size_t)NE * DM * DF * 2;            // 64 MB each
    const size_t o_w2t = o_w1t + sz_w;
    const size_t o_h   = o_w2t + sz_w;
    const size_t sz_h  = (size_t)(2 * T_TOK) * DF * 2;        // 134 MB
    const size_t NEEDED = o_h + sz_h;

    hipMemsetAsync(counts, 0, 64, stream);
    route_kernel<<<T_TOK / 4, 256, 0, stream>>>(x, Wg, counts, lists, pw);

    if (ws_size >= NEEDED) {
        unsigned short* xb  = (unsigned short*)(ws + o_xb);
        unsigned short* w1t = (unsigned short*)(ws + o_w1t);
        unsigned short* w2t = (unsigned short*)(ws + o_w2t);
        unsigned short* H   = (unsigned short*)(ws + o_h);

        hipMemsetAsync(d_out, 0, (size_t)out_size * sizeof(float), stream);
        offsets_kernel<<<1, 64, 0, stream>>>(counts, offsets, table, ntp);
        conv_x_kernel<<<(T_TOK * DM) / (256 * 8), 256, 0, stream>>>(x, xb);
        {
            dim3 g(DM / 64, DF / 64, NE);
            transpose_conv_kernel<DM, DF><<<g, 256, 0, stream>>>(W1, w1t);
        }
        {
            dim3 g(DF / 64, DM / 64, NE);
            transpose_conv_kernel<DF, DM><<<g, 256, 0, stream>>>(W2, w2t);
        }
        // G1: [cnt x 1024] @ W1t -> silu -> H (bf16), 256x256 tiles
        moe_gemm8<DF, DM, 1, true><<<dim3(MAXT * (DF / 256)), 512, 0, stream>>>(
            xb, w1t, counts, offsets, lists, table, ntp, pw, H, nullptr);
        // G2: H @ W2t -> gated atomic-add into out, 256x256 tiles, split-K 2
        moe_gemm8<DM, DF, 2, false><<<dim3(MAXT * (DM / 256) * 2), 512, 0, stream>>>(
            H, w2t, counts, offsets, lists, table, ntp, pw, nullptr, out);
    } else {
        hipMemsetAsync(d_out, 0, (size_t)out_size * sizeof(float), stream);
        dim3 grid(T_TOK / BMF, NE);
        expert_gemm_f32<<<grid, 256, 0, stream>>>(x, W1, W2, counts, lists, pw, out);
    }
}

// Round 2
// 782.164 us; speedup vs baseline: 1.0359x; 1.0359x over previous
//
#include <hip/hip_runtime.h>
#include <hip/hip_bf16.h>
#include <math.h>

#define T_TOK 8192
#define DM 1024
#define DF 4096
#define NE 8
#define MAXT 72    // max 256-row tiles: 64 full + 7 partials + slack

typedef __attribute__((ext_vector_type(4))) float  f32x4;
typedef __attribute__((ext_vector_type(8))) short  s16x8;
typedef __attribute__((ext_vector_type(8))) unsigned short u16x8;

__device__ __forceinline__ unsigned short f2bf(float f) {
    unsigned int u = __builtin_bit_cast(unsigned int, f);
    u = (u + 0x7FFFu + ((u >> 16) & 1u)) >> 16;
    return (unsigned short)u;
}

#define GLDS16(gptr, lptr)                                                         \
    __builtin_amdgcn_global_load_lds(                                              \
        (const __attribute__((address_space(1))) void*)(gptr),                     \
        (__attribute__((address_space(3))) void*)(lptr), 16, 0, 0)

#define BAR() asm volatile("s_barrier" ::: "memory")

template<int W>
__device__ __forceinline__ void waitvm() {
    if constexpr (W == 8)      asm volatile("s_waitcnt vmcnt(8)" ::: "memory");
    else if constexpr (W == 4) asm volatile("s_waitcnt vmcnt(4)" ::: "memory");
    else                       asm volatile("s_waitcnt vmcnt(0)" ::: "memory");
}

// ---------------- Routing ----------------
__global__ __launch_bounds__(256) void route_kernel(
    const float* __restrict__ x, const float* __restrict__ Wg,
    int* __restrict__ counts, int* __restrict__ lists, float* __restrict__ pw)
{
    int tok  = (int)((blockIdx.x * blockDim.x + threadIdx.x) >> 6);
    int lane = threadIdx.x & 63;
    if (tok >= T_TOK) return;

    const float* xr = x + (size_t)tok * DM;
    float acc[NE];
#pragma unroll
    for (int e = 0; e < NE; ++e) acc[e] = 0.f;

    for (int i = lane; i < DM; i += 64) {
        float xv = xr[i];
        const float* wr = Wg + (size_t)i * NE;
#pragma unroll
        for (int e = 0; e < NE; ++e) acc[e] += xv * wr[e];
    }
#pragma unroll
    for (int e = 0; e < NE; ++e) {
#pragma unroll
        for (int off = 32; off > 0; off >>= 1)
            acc[e] += __shfl_xor(acc[e], off, 64);
    }

    if (lane == 0) {
        int i0 = 0; float v0 = acc[0];
#pragma unroll
        for (int e = 1; e < NE; ++e) if (acc[e] > v0) { v0 = acc[e]; i0 = e; }
        int i1 = -1; float v1 = -INFINITY;
#pragma unroll
        for (int e = 0; e < NE; ++e) if (e != i0 && acc[e] > v1) { v1 = acc[e]; i1 = e; }
        float e1 = __expf(v1 - v0);
        float s  = 1.f + e1;
        int p0 = tok * 2, p1 = tok * 2 + 1;
        pw[p0] = 1.f / s;
        pw[p1] = e1 / s;
        int pos0 = atomicAdd(&counts[i0], 1);
        lists[i0 * T_TOK + pos0] = p0;
        int pos1 = atomicAdd(&counts[i1], 1);
        lists[i1 * T_TOK + pos1] = p1;
    }
}

// offsets + 256-row tile table (e<<20 | slot0) + live tile count
__global__ void offsets_kernel(const int* __restrict__ counts, int* __restrict__ offsets,
                               unsigned* __restrict__ table, int* __restrict__ ntp)
{
    if (threadIdx.x == 0) {
        int s = 0, ti = 0;
        for (int e = 0; e < NE; ++e) {
            offsets[e] = s;
            int cnt = counts[e];
            for (int t0 = 0; t0 < cnt; t0 += 256)
                table[ti++] = ((unsigned)e << 20) | (unsigned)t0;
            s += cnt;
        }
        ntp[0] = ti;
        for (; ti < MAXT; ++ti) table[ti] = 0xFFFFFFFFu;
    }
}

// ---------------- x fp32 -> bf16 ----------------
__global__ __launch_bounds__(256) void conv_x_kernel(
    const float* __restrict__ x, unsigned short* __restrict__ xb)
{
    size_t i = ((size_t)blockIdx.x * 256 + threadIdx.x) * 8;
    float4 v0 = *reinterpret_cast<const float4*>(x + i);
    float4 v1 = *reinterpret_cast<const float4*>(x + i + 4);
    u16x8 o;
    o[0] = f2bf(v0.x); o[1] = f2bf(v0.y); o[2] = f2bf(v0.z); o[3] = f2bf(v0.w);
    o[4] = f2bf(v1.x); o[5] = f2bf(v1.y); o[6] = f2bf(v1.z); o[7] = f2bf(v1.w);
    *reinterpret_cast<u16x8*>(xb + i) = o;
}

// ---------------- W [E][K][N] fp32 -> Wt [E][N][K] bf16 (16B/lane both sides) --------
template<int K, int N>
__global__ __launch_bounds__(256) void transpose_conv_kernel(
    const float* __restrict__ W, unsigned short* __restrict__ Wt)
{
    int e  = blockIdx.z;
    int k0 = blockIdx.x * 64;
    int n0 = blockIdx.y * 64;
    const float* We = W + (size_t)e * K * N;
    unsigned short* Wte = Wt + (size_t)e * K * N;

    __shared__ unsigned short t[64][73];
    int c4 = (threadIdx.x & 15) * 4;
    int r  = threadIdx.x >> 4;              // 0..15
#pragma unroll
    for (int i = 0; i < 4; ++i) {
        int rr = r + i * 16;
        float4 v = *reinterpret_cast<const float4*>(We + (size_t)(k0 + rr) * N + n0 + c4);
        t[rr][c4 + 0] = f2bf(v.x); t[rr][c4 + 1] = f2bf(v.y);
        t[rr][c4 + 2] = f2bf(v.z); t[rr][c4 + 3] = f2bf(v.w);
    }
    __syncthreads();
    int kc = (threadIdx.x & 7) * 8;
    int rn = threadIdx.x >> 3;              // 0..31
#pragma unroll
    for (int i = 0; i < 2; ++i) {
        int nn = rn + i * 32;
        u16x8 o;
#pragma unroll
        for (int j = 0; j < 8; ++j) o[j] = t[kc + j][nn];
        *reinterpret_cast<u16x8*>(Wte + (size_t)(n0 + nn) * K + k0 + kc) = o;
    }
}

// ---------------- m201-style 8-phase grouped GEMM ----------------
// BM=256, BN=256, BK=64 split into 2 K-halves of 32. 512 thr, 8 waves (2M x 4N),
// per-wave 128x64, acc[8][4]. LDS 128 KB = 2 operands x ring-of-4 16KB slabs
// (slab = 256 rows x 64B; K-half hs occupies slab hs&3).
// Per K-tile: 4 phases, each {4-8 ds_read_b128; 2 global_load_lds; BAR;
// setprio(1); 16 MFMA; setprio(0); [counted vmcnt]; BAR}.
// Stage schedule: tile kt phases 1-4 stage A(2kt+3), B(2kt+3), A(2kt+4), B(2kt+4).
// Waits: end of p2 -> B(2kt+1) resident (vmcnt(8), issued 4 phases earlier);
//        end of p4 -> B(2kt+2) resident (vmcnt(8)). Never vmcnt(0) except exact tail.
// 64B slab rows make frag reads naturally bank-conflict-free (row parity staggers
// the 16B granules), so no XOR swizzle anywhere.
template<int N, int K, int SPLITK, bool IS_G1>
__global__ __launch_bounds__(512, 2) void moe_gemm9(
    const unsigned short* __restrict__ A,
    const unsigned short* __restrict__ Wt,
    const int* __restrict__ counts, const int* __restrict__ offsets,
    const int* __restrict__ lists, const unsigned* __restrict__ table,
    const int* __restrict__ ntp, const float* __restrict__ pw,
    unsigned short* __restrict__ Hout, float* __restrict__ Oout)
{
    constexpr int NT  = N / 256;
    constexpr int PAN = NT * SPLITK;
    constexpr int KS  = K / SPLITK;
    constexpr int NKT = KS / 64;
    constexpr int NHS = 2 * NKT;            // K-half steps
    static_assert(NKT >= 3, "pipeline depth");

    __shared__ __attribute__((aligned(16))) char lds[131072];
    // A slab s: lds + s*16384 ; B slab s: lds + 65536 + s*16384

    int ntl  = ntp[0];
    int live = ntl * PAN;
    int orig = blockIdx.x;
    if (orig >= live) return;
    int q = live >> 3, r = live & 7;
    int xq = orig & 7, ib = orig >> 3;
    int work = (xq < r ? xq * (q + 1) : r * (q + 1) + (xq - r) * q) + ib;
    int rt    = work / PAN;                 // rt-major: neighbors share A-tile
    int panel = work - rt * PAN;
    int nt    = (SPLITK == 2) ? (panel >> 1) : panel;
    int sk    = (SPLITK == 2) ? (panel & 1) : 0;
    int koff  = sk * KS;

    unsigned te = table[rt];
    int e     = (int)(te >> 20);
    int slot0 = (int)(te & 0xFFFFFu);
    int cnt   = counts[e];
    int off   = offsets[e];
    int ntile = nt * 256;

    int tid  = threadIdx.x;
    int lane = tid & 63;
    int wid  = tid >> 6;
    int wm = wid >> 2;                  // 0..1  (128-row half)
    int wn = wid & 3;                   // 0..3  (64-col quarter)
    int l15 = lane & 15, l4 = lane >> 4;

    const unsigned short* Be = Wt + (size_t)e * N * K;

    // ---- staging source offsets (elements): row r0 = tid>>2 (+u*128), kgroup tid&3
    int kg8 = (tid & 3) * 8;
    int r0  = tid >> 2;                 // 0..127
    unsigned aOff0, aOff1;
    {
#pragma unroll
        for (int u = 0; u < 2; ++u) {
            int sl = slot0 + u * 128 + r0;
            unsigned grow;
            if (IS_G1) grow = (sl < cnt) ? (unsigned)(lists[e * T_TOK + sl] >> 1) : 0u;
            else       grow = (unsigned)(off + ((sl < cnt) ? sl : slot0));
            unsigned v = grow * (unsigned)K + (unsigned)(koff + kg8);
            if (u == 0) aOff0 = v; else aOff1 = v;
        }
    }
    unsigned bOff0 = (unsigned)(ntile + r0)       * (unsigned)K + (unsigned)(koff + kg8);
    unsigned bOff1 = (unsigned)(ntile + 128 + r0) * (unsigned)K + (unsigned)(koff + kg8);

    auto SA = [&](int hs) {
        if (hs < NHS) {
            char* d = lds + (hs & 3) * 16384 + tid * 16;
            GLDS16(A + aOff0 + hs * 32, d);
            GLDS16(A + aOff1 + hs * 32, d + 8192);
        }
    };
    auto SB = [&](int hs) {
        if (hs < NHS) {
            char* d = lds + 65536 + (hs & 3) * 16384 + tid * 16;
            GLDS16(Be + bOff0 + hs * 32, d);
            GLDS16(Be + bOff1 + hs * 32, d + 8192);
        }
    };

    // ---- fragment read bases: lane reads row(+l15)*64B, 16B granule l4
    int aRd = (wm * 128 + l15) * 64 + l4 * 16;
    int bRd = (wn * 64  + l15) * 64 + l4 * 16;

    f32x4 acc[8][4];
#pragma unroll
    for (int m = 0; m < 8; ++m)
#pragma unroll
        for (int n = 0; n < 4; ++n) acc[m][n] = (f32x4){0.f, 0.f, 0.f, 0.f};

    s16x8 af[4], bf[4];
    auto loadA = [&](int hs, int mh) {
        const char* Ab = lds + (hs & 3) * 16384;
#pragma unroll
        for (int m = 0; m < 4; ++m)
            af[m] = *reinterpret_cast<const s16x8*>(Ab + aRd + mh * 4096 + m * 1024);
    };
    auto loadB = [&](int hs) {
        const char* Bb = lds + 65536 + (hs & 3) * 16384;
#pragma unroll
        for (int n = 0; n < 4; ++n)
            bf[n] = *reinterpret_cast<const s16x8*>(Bb + bRd + n * 1024);
    };
    auto mfma16 = [&](int mh) {
        __builtin_amdgcn_s_setprio(1);
#pragma unroll
        for (int n = 0; n < 4; ++n)
#pragma unroll
            for (int m = 0; m < 4; ++m)
                acc[mh * 4 + m][n] = __builtin_amdgcn_mfma_f32_16x16x32_bf16(
                    af[m], bf[n], acc[mh * 4 + m][n], 0, 0, 0);
        __builtin_amdgcn_s_setprio(0);
    };

    // ---- prologue: halves 0,1,2 in flight; B(0) resident before first reads
    SA(0); SB(0); SA(1); SB(1); SA(2); SB(2);
    waitvm<8>();       // allow {A1,B1,A2,B2} outstanding -> A0,B0 done
    BAR();

    // ---- main loop ----
    for (int kt = 0; kt < NKT; ++kt) {
        int hs0 = 2 * kt, hs1 = 2 * kt + 1;
        // p1: (k-half 0, m-half 0)
        loadB(hs0); loadA(hs0, 0); SA(2 * kt + 3);
        BAR();
        mfma16(0);
        BAR();
        // p2: (k-half 0, m-half 1)
        loadA(hs0, 1); SB(2 * kt + 3);
        BAR();
        mfma16(1);
        if (kt < NKT - 1) waitvm<8>(); else waitvm<0>();   // half 2kt+1 resident
        BAR();
        // p3: (k-half 1, m-half 0)
        loadB(hs1); loadA(hs1, 0); SA(2 * kt + 4);
        BAR();
        mfma16(0);
        BAR();
        // p4: (k-half 1, m-half 1)
        loadA(hs1, 1); SB(2 * kt + 4);
        BAR();
        mfma16(1);
        if (kt < NKT - 2)       waitvm<8>();               // half 2kt+2 resident
        else if (kt == NKT - 2) waitvm<4>();
        BAR();
    }

    // ---- epilogue: C/D col = lane&15, row = (lane>>4)*4 + rr ----
#pragma unroll
    for (int m = 0; m < 8; ++m) {
        int trow = wm * 128 + m * 16 + l4 * 4;
#pragma unroll
        for (int rr = 0; rr < 4; ++rr) {
            int slot = slot0 + trow + rr;
            if (slot >= cnt) continue;
            if (IS_G1) {
                unsigned short* hr = Hout + (size_t)(off + slot) * N;
#pragma unroll
                for (int n = 0; n < 4; ++n) {
                    int col = ntile + wn * 64 + n * 16 + l15;
                    float v = acc[m][n][rr];
                    float s = v / (1.f + __expf(-v));
                    hr[col] = f2bf(s);
                }
            } else {
                int p = lists[e * T_TOK + slot];
                float w = pw[p];
                float* orow = Oout + (size_t)(p >> 1) * DM;
#pragma unroll
                for (int n = 0; n < 4; ++n) {
                    int col = ntile + wn * 64 + n * 16 + l15;
                    atomicAdd(orow + col, w * acc[m][n][rr]);
                }
            }
        }
    }
}

// ================= fallback (round-1 validated fp32 path) =================
#define BMF 16
#define BFF 256
__global__ __launch_bounds__(256) void expert_gemm_f32(
    const float* __restrict__ x, const float* __restrict__ W1, const float* __restrict__ W2,
    const int* __restrict__ counts, const int* __restrict__ lists, const float* __restrict__ pw,
    float* __restrict__ out)
{
    int e    = blockIdx.y;
    int tile = blockIdx.x;
    int cnt  = counts[e];
    int start = tile * BMF;
    if (start >= cnt) return;

    __shared__ float xs[BMF][DM];
    __shared__ float hs[BMF][BFF];
    __shared__ int   toks[BMF];
    __shared__ float wgt[BMF];

    int tid = threadIdx.x;
    int nm  = cnt - start; if (nm > BMF) nm = BMF;

    if (tid < BMF) {
        if (tid < nm) {
            int p = lists[e * T_TOK + start + tid];
            toks[tid] = p >> 1;
            wgt[tid]  = pw[p];
        } else { toks[tid] = -1; wgt[tid] = 0.f; }
    }
    __syncthreads();
    for (int m = 0; m < BMF; ++m) {
        int t = toks[m];
        const float* xr = (t >= 0) ? (x + (size_t)t * DM) : nullptr;
        for (int i = tid; i < DM; i += 256) xs[m][i] = (t >= 0) ? xr[i] : 0.f;
    }
    __syncthreads();

    const float* W1e = W1 + (size_t)e * DM * DF;
    const float* W2e = W2 + (size_t)e * DF * DM;
    float acc[BMF][4];
#pragma unroll
    for (int m = 0; m < BMF; ++m)
#pragma unroll
        for (int c = 0; c < 4; ++c) acc[m][c] = 0.f;

    for (int fc = 0; fc < DF; fc += BFF) {
        float hacc[BMF];
#pragma unroll
        for (int m = 0; m < BMF; ++m) hacc[m] = 0.f;
        const float* w1col = W1e + fc + tid;
#pragma unroll 4
        for (int i = 0; i < DM; ++i) {
            float w1v = w1col[(size_t)i * DF];
#pragma unroll
            for (int m = 0; m < BMF; ++m) hacc[m] += xs[m][i] * w1v;
        }
        __syncthreads();
#pragma unroll
        for (int m = 0; m < BMF; ++m) {
            float v = hacc[m];
            hs[m][tid] = v / (1.f + __expf(-v));
        }
        __syncthreads();
        const float* w2base = W2e + (size_t)fc * DM + tid * 4;
        for (int f = 0; f < BFF; ++f) {
            float4 w2v = *reinterpret_cast<const float4*>(w2base + (size_t)f * DM);
#pragma unroll
            for (int m = 0; m < BMF; ++m) {
                float h = hs[m][f];
                acc[m][0] += h * w2v.x; acc[m][1] += h * w2v.y;
                acc[m][2] += h * w2v.z; acc[m][3] += h * w2v.w;
            }
        }
        __syncthreads();
    }
    int c0 = tid * 4;
#pragma unroll
    for (int m = 0; m < BMF; ++m) {
        int t = toks[m];
        if (t < 0) continue;
        float w = wgt[m];
        float* op = out + (size_t)t * DM + c0;
        atomicAdd(op + 0, w * acc[m][0]);
        atomicAdd(op + 1, w * acc[m][1]);
        atomicAdd(op + 2, w * acc[m][2]);
        atomicAdd(op + 3, w * acc[m][3]);
    }
}

// ================= launch =================
extern "C" void kernel_launch(void* const* d_in, const int* in_sizes, int n_in,
                              void* d_out, int out_size, void* d_ws, size_t ws_size,
                              hipStream_t stream)
{
    const float* x  = (const float*)d_in[0];
    const float* Wg = (const float*)d_in[1];
    const float* W1 = (const float*)d_in[2];
    const float* W2 = (const float*)d_in[3];
    float* out = (float*)d_out;

    char* ws = (char*)d_ws;
    int*      counts  = (int*)(ws + 0);
    int*      offsets = (int*)(ws + 64);
    int*      ntp     = (int*)(ws + 128);
    unsigned* table   = (unsigned*)(ws + 256);        // 72*4 = 288 B
    int*      lists   = (int*)(ws + 2048);            // 256 KB
    float*    pw      = (float*)(ws + 2048 + 262144); // 64 KB

    const size_t o_xb  = 524288;
    const size_t sz_xb = (size_t)T_TOK * DM * 2;              // 16 MB
    const size_t o_w1t = o_xb + sz_xb;
    const size_t sz_w  = (size_t)NE * DM * DF * 2;            // 64 MB each
    const size_t o_w2t = o_w1t + sz_w;
    const size_t o_h   = o_w2t + sz_w;
    const size_t sz_h  = (size_t)(2 * T_TOK) * DF * 2;        // 134 MB
    const size_t NEEDED = o_h + sz_h;

    hipMemsetAsync(counts, 0, 64, stream);
    route_kernel<<<T_TOK / 4, 256, 0, stream>>>(x, Wg, counts, lists, pw);

    if (ws_size >= NEEDED) {
        unsigned short* xb  = (unsigned short*)(ws + o_xb);
        unsigned short* w1t = (unsigned short*)(ws + o_w1t);
        unsigned short* w2t = (unsigned short*)(ws + o_w2t);
        unsigned short* H   = (unsigned short*)(ws + o_h);

        hipMemsetAsync(d_out, 0, (size_t)out_size * sizeof(float), stream);
        offsets_kernel<<<1, 64, 0, stream>>>(counts, offsets, table, ntp);
        conv_x_kernel<<<(T_TOK * DM) / (256 * 8), 256, 0, stream>>>(x, xb);
        {
            dim3 g(DM / 64, DF / 64, NE);
            transpose_conv_kernel<DM, DF><<<g, 256, 0, stream>>>(W1, w1t);
        }
        {
            dim3 g(DF / 64, DM / 64, NE);
            transpose_conv_kernel<DF, DM><<<g, 256, 0, stream>>>(W2, w2t);
        }
        // G1: [cnt x 1024] @ W1t -> silu -> H (bf16), 256x256 tiles
        moe_gemm9<DF, DM, 1, true><<<dim3(MAXT * (DF / 256)), 512, 0, stream>>>(
            xb, w1t, counts, offsets, lists, table, ntp, pw, H, nullptr);
        // G2: H @ W2t -> gated atomic-add into out, 256x256 tiles, split-K 2
        moe_gemm9<DM, DF, 2, false><<<dim3(MAXT * (DM / 256) * 2), 512, 0, stream>>>(
            H, w2t, counts, offsets, lists, table, ntp, pw, nullptr, out);
    } else {
        hipMemsetAsync(d_out, 0, (size_t)out_size * sizeof(float), stream);
        dim3 grid(T_TOK / BMF, NE);
        expert_gemm_f32<<<grid, 256, 0, stream>>>(x, W1, W2, counts, lists, pw, out);
    }
}

// Round 3
// 764.584 us; speedup vs baseline: 1.0597x; 1.0230x over previous
//
#include <hip/hip_runtime.h>
#include <hip/hip_bf16.h>
#include <math.h>

#define T_TOK 8192
#define DM 1024
#define DF 4096
#define NE 8
#define MAXT 72    // max 256-row tiles: 64 full + 7 partials + slack

typedef __attribute__((ext_vector_type(4))) float  f32x4;
typedef __attribute__((ext_vector_type(8))) short  s16x8;
typedef __attribute__((ext_vector_type(8))) unsigned short u16x8;

__device__ __forceinline__ unsigned short f2bf(float f) {
    unsigned int u = __builtin_bit_cast(unsigned int, f);
    u = (u + 0x7FFFu + ((u >> 16) & 1u)) >> 16;
    return (unsigned short)u;
}

#define GLDS16(gptr, lptr)                                                         \
    __builtin_amdgcn_global_load_lds(                                              \
        (const __attribute__((address_space(1))) void*)(gptr),                     \
        (__attribute__((address_space(3))) void*)(lptr), 16, 0, 0)

#define BAR()  asm volatile("s_barrier" ::: "memory")
#define SBAR() __builtin_amdgcn_sched_barrier(0)
#define LGKM0() asm volatile("s_waitcnt lgkmcnt(0)" ::: "memory")

template<int W>
__device__ __forceinline__ void waitvm() {
    if constexpr (W == 8)      asm volatile("s_waitcnt vmcnt(8)" ::: "memory");
    else if constexpr (W == 4) asm volatile("s_waitcnt vmcnt(4)" ::: "memory");
    else                       asm volatile("s_waitcnt vmcnt(0)" ::: "memory");
}

// ---------------- Routing ----------------
__global__ __launch_bounds__(256) void route_kernel(
    const float* __restrict__ x, const float* __restrict__ Wg,
    int* __restrict__ counts, int* __restrict__ lists, float* __restrict__ pw)
{
    int tok  = (int)((blockIdx.x * blockDim.x + threadIdx.x) >> 6);
    int lane = threadIdx.x & 63;
    if (tok >= T_TOK) return;

    const float* xr = x + (size_t)tok * DM;
    float acc[NE];
#pragma unroll
    for (int e = 0; e < NE; ++e) acc[e] = 0.f;

    for (int i = lane; i < DM; i += 64) {
        float xv = xr[i];
        const float* wr = Wg + (size_t)i * NE;
#pragma unroll
        for (int e = 0; e < NE; ++e) acc[e] += xv * wr[e];
    }
#pragma unroll
    for (int e = 0; e < NE; ++e) {
#pragma unroll
        for (int off = 32; off > 0; off >>= 1)
            acc[e] += __shfl_xor(acc[e], off, 64);
    }

    if (lane == 0) {
        int i0 = 0; float v0 = acc[0];
#pragma unroll
        for (int e = 1; e < NE; ++e) if (acc[e] > v0) { v0 = acc[e]; i0 = e; }
        int i1 = -1; float v1 = -INFINITY;
#pragma unroll
        for (int e = 0; e < NE; ++e) if (e != i0 && acc[e] > v1) { v1 = acc[e]; i1 = e; }
        float e1 = __expf(v1 - v0);
        float s  = 1.f + e1;
        int p0 = tok * 2, p1 = tok * 2 + 1;
        pw[p0] = 1.f / s;
        pw[p1] = e1 / s;
        int pos0 = atomicAdd(&counts[i0], 1);
        lists[i0 * T_TOK + pos0] = p0;
        int pos1 = atomicAdd(&counts[i1], 1);
        lists[i1 * T_TOK + pos1] = p1;
    }
}

// offsets + 256-row tile table (e<<20 | slot0) + live tile count
__global__ void offsets_kernel(const int* __restrict__ counts, int* __restrict__ offsets,
                               unsigned* __restrict__ table, int* __restrict__ ntp)
{
    if (threadIdx.x == 0) {
        int s = 0, ti = 0;
        for (int e = 0; e < NE; ++e) {
            offsets[e] = s;
            int cnt = counts[e];
            for (int t0 = 0; t0 < cnt; t0 += 256)
                table[ti++] = ((unsigned)e << 20) | (unsigned)t0;
            s += cnt;
        }
        ntp[0] = ti;
        for (; ti < MAXT; ++ti) table[ti] = 0xFFFFFFFFu;
    }
}

// ---------------- x fp32 -> bf16 ----------------
__global__ __launch_bounds__(256) void conv_x_kernel(
    const float* __restrict__ x, unsigned short* __restrict__ xb)
{
    size_t i = ((size_t)blockIdx.x * 256 + threadIdx.x) * 8;
    float4 v0 = *reinterpret_cast<const float4*>(x + i);
    float4 v1 = *reinterpret_cast<const float4*>(x + i + 4);
    u16x8 o;
    o[0] = f2bf(v0.x); o[1] = f2bf(v0.y); o[2] = f2bf(v0.z); o[3] = f2bf(v0.w);
    o[4] = f2bf(v1.x); o[5] = f2bf(v1.y); o[6] = f2bf(v1.z); o[7] = f2bf(v1.w);
    *reinterpret_cast<u16x8*>(xb + i) = o;
}

// ---------------- W [E][K][N] fp32 -> Wt [E][N][K] bf16 (16B/lane both sides) --------
template<int K, int N>
__global__ __launch_bounds__(256) void transpose_conv_kernel(
    const float* __restrict__ W, unsigned short* __restrict__ Wt)
{
    int e  = blockIdx.z;
    int k0 = blockIdx.x * 64;
    int n0 = blockIdx.y * 64;
    const float* We = W + (size_t)e * K * N;
    unsigned short* Wte = Wt + (size_t)e * K * N;

    __shared__ unsigned short t[64][73];
    int c4 = (threadIdx.x & 15) * 4;
    int r  = threadIdx.x >> 4;              // 0..15
#pragma unroll
    for (int i = 0; i < 4; ++i) {
        int rr = r + i * 16;
        float4 v = *reinterpret_cast<const float4*>(We + (size_t)(k0 + rr) * N + n0 + c4);
        t[rr][c4 + 0] = f2bf(v.x); t[rr][c4 + 1] = f2bf(v.y);
        t[rr][c4 + 2] = f2bf(v.z); t[rr][c4 + 3] = f2bf(v.w);
    }
    __syncthreads();
    int kc = (threadIdx.x & 7) * 8;
    int rn = threadIdx.x >> 3;              // 0..31
#pragma unroll
    for (int i = 0; i < 2; ++i) {
        int nn = rn + i * 32;
        u16x8 o;
#pragma unroll
        for (int j = 0; j < 8; ++j) o[j] = t[kc + j][nn];
        *reinterpret_cast<u16x8*>(Wte + (size_t)(n0 + nn) * K + k0 + kc) = o;
    }
}

// ---------------- m201-faithful 8-phase grouped GEMM ----------------
// BM=256, BN=256, BK=64 = 2 K-halves of 32. 512 thr, 8 waves (2M x 4N),
// per-wave 128x64, acc[8][4]. LDS 128 KB = 2 operands x ring-of-4 16KB slabs
// (slab = 256 rows x 64B, K-half hs -> slab hs&3).
// Phase = {ds_reads; 1 half-stage (2 GLDS); sched_barrier; s_barrier;
//          lgkmcnt(0); sched_barrier; setprio(1); 16 MFMA; setprio(0);
//          sched_barrier; [counted vmcnt(8), never 0 till tail]; s_barrier}.
// Conflict fix vs r2 (1.34e7 SQ_LDS_BANK_CONFLICT): 4x16B slots per 64B row,
// store granule g = (tid&3)^((tid>>3)&3), read slot s = l4^((l15>>1)&3)
// -> 2 lanes/bank per 16-lane group (involution verified).
template<int N, int K, int SPLITK, bool IS_G1>
__global__ __launch_bounds__(512, 2) void moe_gemm10(
    const unsigned short* __restrict__ A,
    const unsigned short* __restrict__ Wt,
    const int* __restrict__ counts, const int* __restrict__ offsets,
    const int* __restrict__ lists, const unsigned* __restrict__ table,
    const int* __restrict__ ntp, const float* __restrict__ pw,
    unsigned short* __restrict__ Hout, float* __restrict__ Oout)
{
    constexpr int NT  = N / 256;
    constexpr int PAN = NT * SPLITK;
    constexpr int KS  = K / SPLITK;
    constexpr int NKT = KS / 64;
    constexpr int NHS = 2 * NKT;            // K-half steps
    static_assert(NKT >= 3, "pipeline depth");

    __shared__ __attribute__((aligned(16))) char lds[131072];
    // A slab s: lds + s*16384 ; B slab s: lds + 65536 + s*16384

    int ntl  = ntp[0];
    int live = ntl * PAN;
    int orig = blockIdx.x;
    if (orig >= live) return;
    int q = live >> 3, r = live & 7;
    int xq = orig & 7, ib = orig >> 3;
    int work = (xq < r ? xq * (q + 1) : r * (q + 1) + (xq - r) * q) + ib;
    int rt    = work / PAN;                 // rt-major: neighbors share A-tile
    int panel = work - rt * PAN;
    int nt    = (SPLITK == 2) ? (panel >> 1) : panel;
    int sk    = (SPLITK == 2) ? (panel & 1) : 0;
    int koff  = sk * KS;

    unsigned te = table[rt];
    int e     = (int)(te >> 20);
    int slot0 = (int)(te & 0xFFFFFu);
    int cnt   = counts[e];
    int off   = offsets[e];
    int ntile = nt * 256;

    int tid  = threadIdx.x;
    int lane = tid & 63;
    int wid  = tid >> 6;
    int wm = wid >> 2;                  // 0..1  (128-row half)
    int wn = wid & 3;                   // 0..3  (64-col quarter)
    int l15 = lane & 15, l4 = lane >> 4;

    const unsigned short* Be = Wt + (size_t)e * N * K;

    // ---- staging source offsets. LDS dest linear: row r0 = tid>>2, slot tid&3.
    // Pre-swizzled source granule g = (tid&3) ^ ((tid>>3)&3)  [(r0>>1)&3].
    int kg8 = (((tid & 3) ^ ((tid >> 3) & 3))) * 8;
    int r0  = tid >> 2;                 // 0..127
    unsigned aOff0, aOff1;
    {
#pragma unroll
        for (int u = 0; u < 2; ++u) {
            int sl = slot0 + u * 128 + r0;
            unsigned grow;
            if (IS_G1) grow = (sl < cnt) ? (unsigned)(lists[e * T_TOK + sl] >> 1) : 0u;
            else       grow = (unsigned)(off + ((sl < cnt) ? sl : slot0));
            unsigned v = grow * (unsigned)K + (unsigned)(koff + kg8);
            if (u == 0) aOff0 = v; else aOff1 = v;
        }
    }
    unsigned bOff0 = (unsigned)(ntile + r0)       * (unsigned)K + (unsigned)(koff + kg8);
    unsigned bOff1 = (unsigned)(ntile + 128 + r0) * (unsigned)K + (unsigned)(koff + kg8);

    auto SA = [&](int hs) {
        if (hs < NHS) {
            char* d = lds + (hs & 3) * 16384 + tid * 16;
            GLDS16(A + aOff0 + hs * 32, d);
            GLDS16(A + aOff1 + hs * 32, d + 8192);
        }
    };
    auto SB = [&](int hs) {
        if (hs < NHS) {
            char* d = lds + 65536 + (hs & 3) * 16384 + tid * 16;
            GLDS16(Be + bOff0 + hs * 32, d);
            GLDS16(Be + bOff1 + hs * 32, d + 8192);
        }
    };

    // ---- fragment read bases: row*64B + swizzled 16B slot (row-term vanishes
    // since m*16 and wm*128, wn*64 are ==0 mod the slot hash inputs).
    int swzs = (l4 ^ ((l15 >> 1) & 3)) * 16;
    int aRd = (wm * 128 + l15) * 64 + swzs;
    int bRd = (wn * 64  + l15) * 64 + swzs;

    f32x4 acc[8][4];
#pragma unroll
    for (int m = 0; m < 8; ++m)
#pragma unroll
        for (int n = 0; n < 4; ++n) acc[m][n] = (f32x4){0.f, 0.f, 0.f, 0.f};

    s16x8 af[4], bf[4];
    auto loadA = [&](int hs, int mh) {
        const char* Ab = lds + (hs & 3) * 16384;
#pragma unroll
        for (int m = 0; m < 4; ++m)
            af[m] = *reinterpret_cast<const s16x8*>(Ab + aRd + mh * 4096 + m * 1024);
    };
    auto loadB = [&](int hs) {
        const char* Bb = lds + 65536 + (hs & 3) * 16384;
#pragma unroll
        for (int n = 0; n < 4; ++n)
            bf[n] = *reinterpret_cast<const s16x8*>(Bb + bRd + n * 1024);
    };
    auto mfma16 = [&](int mh) {
        __builtin_amdgcn_s_setprio(1);
#pragma unroll
        for (int n = 0; n < 4; ++n)
#pragma unroll
            for (int m = 0; m < 4; ++m)
                acc[mh * 4 + m][n] = __builtin_amdgcn_mfma_f32_16x16x32_bf16(
                    af[m], bf[n], acc[mh * 4 + m][n], 0, 0, 0);
        __builtin_amdgcn_s_setprio(0);
    };

    // ---- prologue: halves 0,1,2 in flight; half 0 resident before first reads
    SA(0); SB(0); SA(1); SB(1); SA(2); SB(2);
    waitvm<8>();       // {A1,B1,A2,B2} may stay outstanding -> A0,B0 done
    BAR();

    // ---- main loop: 4 pinned phases per K-tile ----
    for (int kt = 0; kt < NKT; ++kt) {
        int hs0 = 2 * kt, hs1 = 2 * kt + 1;
        // p1: (k-half 0, m-half 0)
        loadB(hs0); loadA(hs0, 0); SA(2 * kt + 3);
        SBAR(); BAR(); LGKM0(); SBAR();
        mfma16(0);
        SBAR(); BAR();
        // p2: (k-half 0, m-half 1)
        loadA(hs0, 1); SB(2 * kt + 3);
        SBAR(); BAR(); LGKM0(); SBAR();
        mfma16(1);
        SBAR();
        if (kt < NKT - 1) waitvm<8>(); else waitvm<0>();   // half 2kt+1 resident
        BAR();
        // p3: (k-half 1, m-half 0)
        loadB(hs1); loadA(hs1, 0); SA(2 * kt + 4);
        SBAR(); BAR(); LGKM0(); SBAR();
        mfma16(0);
        SBAR(); BAR();
        // p4: (k-half 1, m-half 1)
        loadA(hs1, 1); SB(2 * kt + 4);
        SBAR(); BAR(); LGKM0(); SBAR();
        mfma16(1);
        SBAR();
        if (kt < NKT - 2)       waitvm<8>();               // half 2kt+2 resident
        else if (kt == NKT - 2) waitvm<4>();
        BAR();
    }

    // ---- epilogue: C/D col = lane&15, row = (lane>>4)*4 + rr ----
#pragma unroll
    for (int m = 0; m < 8; ++m) {
        int trow = wm * 128 + m * 16 + l4 * 4;
#pragma unroll
        for (int rr = 0; rr < 4; ++rr) {
            int slot = slot0 + trow + rr;
            if (slot >= cnt) continue;
            if (IS_G1) {
                unsigned short* hr = Hout + (size_t)(off + slot) * N;
#pragma unroll
                for (int n = 0; n < 4; ++n) {
                    int col = ntile + wn * 64 + n * 16 + l15;
                    float v = acc[m][n][rr];
                    float s = v / (1.f + __expf(-v));
                    hr[col] = f2bf(s);
                }
            } else {
                int p = lists[e * T_TOK + slot];
                float w = pw[p];
                float* orow = Oout + (size_t)(p >> 1) * DM;
#pragma unroll
                for (int n = 0; n < 4; ++n) {
                    int col = ntile + wn * 64 + n * 16 + l15;
                    atomicAdd(orow + col, w * acc[m][n][rr]);
                }
            }
        }
    }
}

// ================= fallback (round-1 validated fp32 path) =================
#define BMF 16
#define BFF 256
__global__ __launch_bounds__(256) void expert_gemm_f32(
    const float* __restrict__ x, const float* __restrict__ W1, const float* __restrict__ W2,
    const int* __restrict__ counts, const int* __restrict__ lists, const float* __restrict__ pw,
    float* __restrict__ out)
{
    int e    = blockIdx.y;
    int tile = blockIdx.x;
    int cnt  = counts[e];
    int start = tile * BMF;
    if (start >= cnt) return;

    __shared__ float xs[BMF][DM];
    __shared__ float hs[BMF][BFF];
    __shared__ int   toks[BMF];
    __shared__ float wgt[BMF];

    int tid = threadIdx.x;
    int nm  = cnt - start; if (nm > BMF) nm = BMF;

    if (tid < BMF) {
        if (tid < nm) {
            int p = lists[e * T_TOK + start + tid];
            toks[tid] = p >> 1;
            wgt[tid]  = pw[p];
        } else { toks[tid] = -1; wgt[tid] = 0.f; }
    }
    __syncthreads();
    for (int m = 0; m < BMF; ++m) {
        int t = toks[m];
        const float* xr = (t >= 0) ? (x + (size_t)t * DM) : nullptr;
        for (int i = tid; i < DM; i += 256) xs[m][i] = (t >= 0) ? xr[i] : 0.f;
    }
    __syncthreads();

    const float* W1e = W1 + (size_t)e * DM * DF;
    const float* W2e = W2 + (size_t)e * DF * DM;
    float acc[BMF][4];
#pragma unroll
    for (int m = 0; m < BMF; ++m)
#pragma unroll
        for (int c = 0; c < 4; ++c) acc[m][c] = 0.f;

    for (int fc = 0; fc < DF; fc += BFF) {
        float hacc[BMF];
#pragma unroll
        for (int m = 0; m < BMF; ++m) hacc[m] = 0.f;
        const float* w1col = W1e + fc + tid;
#pragma unroll 4
        for (int i = 0; i < DM; ++i) {
            float w1v = w1col[(size_t)i * DF];
#pragma unroll
            for (int m = 0; m < BMF; ++m) hacc[m] += xs[m][i] * w1v;
        }
        __syncthreads();
#pragma unroll
        for (int m = 0; m < BMF; ++m) {
            float v = hacc[m];
            hs[m][tid] = v / (1.f + __expf(-v));
        }
        __syncthreads();
        const float* w2base = W2e + (size_t)fc * DM + tid * 4;
        for (int f = 0; f < BFF; ++f) {
            float4 w2v = *reinterpret_cast<const float4*>(w2base + (size_t)f * DM);
#pragma unroll
            for (int m = 0; m < BMF; ++m) {
                float h = hs[m][f];
                acc[m][0] += h * w2v.x; acc[m][1] += h * w2v.y;
                acc[m][2] += h * w2v.z; acc[m][3] += h * w2v.w;
            }
        }
        __syncthreads();
    }
    int c0 = tid * 4;
#pragma unroll
    for (int m = 0; m < BMF; ++m) {
        int t = toks[m];
        if (t < 0) continue;
        float w = wgt[m];
        float* op = out + (size_t)t * DM + c0;
        atomicAdd(op + 0, w * acc[m][0]);
        atomicAdd(op + 1, w * acc[m][1]);
        atomicAdd(op + 2, w * acc[m][2]);
        atomicAdd(op + 3, w * acc[m][3]);
    }
}

// ================= launch =================
extern "C" void kernel_launch(void* const* d_in, const int* in_sizes, int n_in,
                              void* d_out, int out_size, void* d_ws, size_t ws_size,
                              hipStream_t stream)
{
    const float* x  = (const float*)d_in[0];
    const float* Wg = (const float*)d_in[1];
    const float* W1 = (const float*)d_in[2];
    const float* W2 = (const float*)d_in[3];
    float* out = (float*)d_out;

    char* ws = (char*)d_ws;
    int*      counts  = (int*)(ws + 0);
    int*      offsets = (int*)(ws + 64);
    int*      ntp     = (int*)(ws + 128);
    unsigned* table   = (unsigned*)(ws + 256);        // 72*4 = 288 B
    int*      lists   = (int*)(ws + 2048);            // 256 KB
    float*    pw      = (float*)(ws + 2048 + 262144); // 64 KB

    const size_t o_xb  = 524288;
    const size_t sz_xb = (size_t)T_TOK * DM * 2;              // 16 MB
    const size_t o_w1t = o_xb + sz_xb;
    const size_t sz_w  = (size_t)NE * DM * DF * 2;            // 64 MB each
    const size_t o_w2t = o_w1t + sz_w;
    const size_t o_h   = o_w2t + sz_w;
    const size_t sz_h  = (size_t)(2 * T_TOK) * DF * 2;        // 134 MB
    const size_t NEEDED = o_h + sz_h;

    hipMemsetAsync(counts, 0, 64, stream);
    route_kernel<<<T_TOK / 4, 256, 0, stream>>>(x, Wg, counts, lists, pw);

    if (ws_size >= NEEDED) {
        unsigned short* xb  = (unsigned short*)(ws + o_xb);
        unsigned short* w1t = (unsigned short*)(ws + o_w1t);
        unsigned short* w2t = (unsigned short*)(ws + o_w2t);
        unsigned short* H   = (unsigned short*)(ws + o_h);

        hipMemsetAsync(d_out, 0, (size_t)out_size * sizeof(float), stream);
        offsets_kernel<<<1, 64, 0, stream>>>(counts, offsets, table, ntp);
        conv_x_kernel<<<(T_TOK * DM) / (256 * 8), 256, 0, stream>>>(x, xb);
        {
            dim3 g(DM / 64, DF / 64, NE);
            transpose_conv_kernel<DM, DF><<<g, 256, 0, stream>>>(W1, w1t);
        }
        {
            dim3 g(DF / 64, DM / 64, NE);
            transpose_conv_kernel<DF, DM><<<g, 256, 0, stream>>>(W2, w2t);
        }
        // G1: [cnt x 1024] @ W1t -> silu -> H (bf16), 256x256 tiles
        moe_gemm10<DF, DM, 1, true><<<dim3(MAXT * (DF / 256)), 512, 0, stream>>>(
            xb, w1t, counts, offsets, lists, table, ntp, pw, H, nullptr);
        // G2: H @ W2t -> gated atomic-add into out, 256x256 tiles, split-K 2
        moe_gemm10<DM, DF, 2, false><<<dim3(MAXT * (DM / 256) * 2), 512, 0, stream>>>(
            H, w2t, counts, offsets, lists, table, ntp, pw, nullptr, out);
    } else {
        hipMemsetAsync(d_out, 0, (size_t)out_size * sizeof(float), stream);
        dim3 grid(T_TOK / BMF, NE);
        expert_gemm_f32<<<grid, 256, 0, stream>>>(x, W1, W2, counts, lists, pw, out);
    }
}

// Round 4
// 695.312 us; speedup vs baseline: 1.1653x; 1.0996x over previous
//
#include <hip/hip_runtime.h>
#include <hip/hip_bf16.h>
#include <math.h>

#define T_TOK 8192
#define DM 1024
#define DF 4096
#define NE 8
#define MAXT 72    // max 256-row tiles: 64 full + 7 partials + slack

typedef __attribute__((ext_vector_type(4))) float  f32x4;
typedef __attribute__((ext_vector_type(8))) short  s16x8;
typedef __attribute__((ext_vector_type(8))) unsigned short u16x8;
typedef __attribute__((ext_vector_type(4))) unsigned short u16x4;

__device__ __forceinline__ unsigned short f2bf(float f) {
    unsigned int u = __builtin_bit_cast(unsigned int, f);
    u = (u + 0x7FFFu + ((u >> 16) & 1u)) >> 16;
    return (unsigned short)u;
}

#define GLDS16(gptr, lptr)                                                         \
    __builtin_amdgcn_global_load_lds(                                              \
        (const __attribute__((address_space(1))) void*)(gptr),                     \
        (__attribute__((address_space(3))) void*)(lptr), 16, 0, 0)

#define BAR() asm volatile("s_barrier" ::: "memory")

template<int W>
__device__ __forceinline__ void waitvm() {
    if constexpr (W == 6)      asm volatile("s_waitcnt vmcnt(6)" ::: "memory");
    else if constexpr (W == 3) asm volatile("s_waitcnt vmcnt(3)" ::: "memory");
    else                       asm volatile("s_waitcnt vmcnt(0)" ::: "memory");
}

// ---------------- Routing (+ fused x fp32->bf16 conversion) ----------------
__global__ __launch_bounds__(256) void route_kernel(
    const float* __restrict__ x, const float* __restrict__ Wg,
    int* __restrict__ counts, int* __restrict__ lists, float* __restrict__ pw,
    unsigned short* __restrict__ xb)
{
    int tok  = (int)((blockIdx.x * blockDim.x + threadIdx.x) >> 6);
    int lane = threadIdx.x & 63;
    if (tok >= T_TOK) return;

    const float* xr = x + (size_t)tok * DM;
    float acc[NE];
#pragma unroll
    for (int e = 0; e < NE; ++e) acc[e] = 0.f;

    for (int i = lane; i < DM; i += 64) {
        float xv = xr[i];
        const float* wr = Wg + (size_t)i * NE;
#pragma unroll
        for (int e = 0; e < NE; ++e) acc[e] += xv * wr[e];
    }

    // fused bf16 conversion of this token's row (re-reads from L1/L2, hot)
    if (xb) {
        unsigned short* xrow = xb + (size_t)tok * DM;
#pragma unroll
        for (int i = lane * 4; i < DM; i += 256) {
            float4 v = *reinterpret_cast<const float4*>(xr + i);
            u16x4 o;
            o[0] = f2bf(v.x); o[1] = f2bf(v.y); o[2] = f2bf(v.z); o[3] = f2bf(v.w);
            *reinterpret_cast<u16x4*>(xrow + i) = o;
        }
    }

#pragma unroll
    for (int e = 0; e < NE; ++e) {
#pragma unroll
        for (int off = 32; off > 0; off >>= 1)
            acc[e] += __shfl_xor(acc[e], off, 64);
    }

    if (lane == 0) {
        int i0 = 0; float v0 = acc[0];
#pragma unroll
        for (int e = 1; e < NE; ++e) if (acc[e] > v0) { v0 = acc[e]; i0 = e; }
        int i1 = -1; float v1 = -INFINITY;
#pragma unroll
        for (int e = 0; e < NE; ++e) if (e != i0 && acc[e] > v1) { v1 = acc[e]; i1 = e; }
        float e1 = __expf(v1 - v0);
        float s  = 1.f + e1;
        int p0 = tok * 2, p1 = tok * 2 + 1;
        pw[p0] = 1.f / s;
        pw[p1] = e1 / s;
        int pos0 = atomicAdd(&counts[i0], 1);
        lists[i0 * T_TOK + pos0] = p0;
        int pos1 = atomicAdd(&counts[i1], 1);
        lists[i1 * T_TOK + pos1] = p1;
    }
}

// offsets + 256-row tile table (e<<20 | slot0) + live tile count
__global__ void offsets_kernel(const int* __restrict__ counts, int* __restrict__ offsets,
                               unsigned* __restrict__ table, int* __restrict__ ntp)
{
    if (threadIdx.x == 0) {
        int s = 0, ti = 0;
        for (int e = 0; e < NE; ++e) {
            offsets[e] = s;
            int cnt = counts[e];
            for (int t0 = 0; t0 < cnt; t0 += 256)
                table[ti++] = ((unsigned)e << 20) | (unsigned)t0;
            s += cnt;
        }
        ntp[0] = ti;
        for (; ti < MAXT; ++ti) table[ti] = 0xFFFFFFFFu;
    }
}

// ---------------- W [E][K][N] fp32 -> Wt [E][N][K] bf16 (16B/lane both sides) --------
template<int K, int N>
__global__ __launch_bounds__(256) void transpose_conv_kernel(
    const float* __restrict__ W, unsigned short* __restrict__ Wt)
{
    int e  = blockIdx.z;
    int k0 = blockIdx.x * 64;
    int n0 = blockIdx.y * 64;
    const float* We = W + (size_t)e * K * N;
    unsigned short* Wte = Wt + (size_t)e * K * N;

    __shared__ unsigned short t[64][73];
    int c4 = (threadIdx.x & 15) * 4;
    int r  = threadIdx.x >> 4;              // 0..15
#pragma unroll
    for (int i = 0; i < 4; ++i) {
        int rr = r + i * 16;
        float4 v = *reinterpret_cast<const float4*>(We + (size_t)(k0 + rr) * N + n0 + c4);
        t[rr][c4 + 0] = f2bf(v.x); t[rr][c4 + 1] = f2bf(v.y);
        t[rr][c4 + 2] = f2bf(v.z); t[rr][c4 + 3] = f2bf(v.w);
    }
    __syncthreads();
    int kc = (threadIdx.x & 7) * 8;
    int rn = threadIdx.x >> 3;              // 0..31
#pragma unroll
    for (int i = 0; i < 2; ++i) {
        int nn = rn + i * 32;
        u16x8 o;
#pragma unroll
        for (int j = 0; j < 8; ++j) o[j] = t[kc + j][nn];
        *reinterpret_cast<u16x8*>(Wte + (size_t)(n0 + nn) * K + k0 + kc) = o;
    }
}

// ---------------- occupancy-first grouped GEMM (r0 core + ring-of-3 prefetch) -------
// BM=256, BN=128, BK=32, 512 thr, 8 waves (4M x 2N), per-wave 64x64.
// Registers <=128/wave (acc 64 + ~60) -> 2 blocks/CU = 16 waves/CU (cross-block
// overlap is the util source; 1-block/CU deep pipelines measured WORSE r1-r3).
// CHANGE vs r0 (the round's single A/B variable): prefetch ring 2 -> 3 slabs,
// counted vmcnt(6) instead of vmcnt(3) -> 2 chunk-periods of load cover.
// LDS 72 KB: A 3x16K + B 3x8K; 2 blocks/CU = 144 KB <= 160 KB.
// Swizzle (measured 0 conflicts in r0): store granule (tid&3)^((tid>>3)&3),
// read slot l4^((l15>>1)&3).
template<int N, int K, int SPLITK, bool IS_G1>
__global__ __launch_bounds__(512, 4) void moe_gemm11(
    const unsigned short* __restrict__ A,
    const unsigned short* __restrict__ Wt,
    const int* __restrict__ counts, const int* __restrict__ offsets,
    const int* __restrict__ lists, const unsigned* __restrict__ table,
    const int* __restrict__ ntp, const float* __restrict__ pw,
    unsigned short* __restrict__ Hout, float* __restrict__ Oout)
{
    constexpr int NT  = N / 128;
    constexpr int PAN = NT * SPLITK;
    constexpr int KS  = K / SPLITK;
    constexpr int NC  = KS / 32;
    static_assert(NC >= 4, "pipeline depth");

    __shared__ __attribute__((aligned(16))) char lds[73728];
    // A slot s: lds + s*16384 (256 rows x 64B); B slot s: lds + 49152 + s*8192 (128 x 64B)

    int ntl  = ntp[0];
    int live = ntl * PAN;
    int orig = blockIdx.x;
    if (orig >= live) return;
    int q = live >> 3, r = live & 7;
    int xq = orig & 7, ib = orig >> 3;
    int work = (xq < r ? xq * (q + 1) : r * (q + 1) + (xq - r) * q) + ib;
    int rt    = work / PAN;                 // rt-major: neighbors share A-tile
    int panel = work - rt * PAN;
    int nt    = panel >> (SPLITK - 1);      // SPLITK is 1 or 2
    int sk    = panel & (SPLITK - 1);
    int koff  = sk * KS;

    unsigned te = table[rt];
    int e     = (int)(te >> 20);
    int slot0 = (int)(te & 0xFFFFFu);
    int cnt   = counts[e];
    int off   = offsets[e];
    int ntile = nt * 128;

    int tid  = threadIdx.x;
    int lane = tid & 63;
    int wid  = tid >> 6;
    int wm = wid >> 1;                  // 0..3
    int wn = wid & 1;                   // 0..1
    int l15 = lane & 15, l4 = lane >> 4;

    const unsigned short* Be = Wt + (size_t)e * N * K;

    // ---- staging offsets (elements). swizzle: granule ^= (row>>1)&3 ----
    int ssw = ((tid & 3) ^ ((tid >> 3) & 3)) * 8;
    unsigned aOff0, aOff1, bOff;
    {
        int r0 = tid >> 2;                  // 0..127
#pragma unroll
        for (int u = 0; u < 2; ++u) {
            int sl = slot0 + u * 128 + r0;
            unsigned grow;
            if (IS_G1) grow = (sl < cnt) ? (unsigned)(lists[e * T_TOK + sl] >> 1) : 0u;
            else       grow = (unsigned)(off + ((sl < cnt) ? sl : slot0));
            unsigned v = grow * (unsigned)K + (unsigned)(koff + ssw);
            if (u == 0) aOff0 = v; else aOff1 = v;
        }
        bOff = (unsigned)(ntile + r0) * (unsigned)K + (unsigned)(koff + ssw);
    }

    auto stage = [&](int s, int c) {
        int ko = c * 32;
        char* dA = lds + s * 16384 + tid * 16;
        char* dB = lds + 49152 + s * 8192 + tid * 16;
        GLDS16(A + aOff0 + ko, dA);
        GLDS16(A + aOff1 + ko, dA + 8192);
        GLDS16(Be + bOff + ko, dB);
    };

    // ---- fragment read bases (swizzled; row stride 64B) ----
    int swzb = (l4 ^ ((l15 >> 1) & 3)) * 16;
    int aRd = (wm * 64 + l15) * 64 + swzb;
    int bRd = (wn * 64 + l15) * 64 + swzb;

    f32x4 acc[4][4];
#pragma unroll
    for (int m = 0; m < 4; ++m)
#pragma unroll
        for (int n = 0; n < 4; ++n) acc[m][n] = (f32x4){0.f, 0.f, 0.f, 0.f};

    auto compute = [&](int s) {
        const char* Ab = lds + s * 16384;
        const char* Bb = lds + 49152 + s * 8192;
        s16x8 af[4];
#pragma unroll
        for (int m = 0; m < 4; ++m)
            af[m] = *reinterpret_cast<const s16x8*>(Ab + aRd + m * 1024);
        __builtin_amdgcn_s_setprio(1);
#pragma unroll
        for (int n = 0; n < 4; ++n) {
            s16x8 bf = *reinterpret_cast<const s16x8*>(Bb + bRd + n * 1024);
#pragma unroll
            for (int m = 0; m < 4; ++m)
                acc[m][n] = __builtin_amdgcn_mfma_f32_16x16x32_bf16(af[m], bf, acc[m][n], 0, 0, 0);
        }
        __builtin_amdgcn_s_setprio(0);
    };

    // ---- pipeline: 3-slot ring, depth-3 prefetch, counted vmcnt(6) ----
    stage(0, 0); stage(1, 1); stage(2, 2);
    int sslot = 0;
    for (int c = 0; c < NC; ++c) {
        if (c + 2 < NC)      waitvm<6>();   // chunk c done; c+1,c+2 in flight
        else if (c + 1 < NC) waitvm<3>();
        else                 waitvm<0>();
        BAR();
        compute(sslot);
        BAR();
        if (c + 3 < NC) stage(sslot, c + 3);
        sslot = (sslot == 2) ? 0 : sslot + 1;
    }

    // ---- epilogue: C/D col = lane&15, row = (lane>>4)*4 + rr ----
#pragma unroll
    for (int m = 0; m < 4; ++m) {
        int trow = wm * 64 + m * 16 + l4 * 4;
#pragma unroll
        for (int rr = 0; rr < 4; ++rr) {
            int slot = slot0 + trow + rr;
            if (slot >= cnt) continue;
            if (IS_G1) {
                unsigned short* hr = Hout + (size_t)(off + slot) * N;
#pragma unroll
                for (int n = 0; n < 4; ++n) {
                    int col = ntile + wn * 64 + n * 16 + l15;
                    float v = acc[m][n][rr];
                    float s = v / (1.f + __expf(-v));
                    hr[col] = f2bf(s);
                }
            } else {
                int p = lists[e * T_TOK + slot];
                float w = pw[p];
                float* orow = Oout + (size_t)(p >> 1) * DM;
#pragma unroll
                for (int n = 0; n < 4; ++n) {
                    int col = ntile + wn * 64 + n * 16 + l15;
                    atomicAdd(orow + col, w * acc[m][n][rr]);
                }
            }
        }
    }
}

// ================= fallback (round-1 validated fp32 path) =================
#define BMF 16
#define BFF 256
__global__ __launch_bounds__(256) void expert_gemm_f32(
    const float* __restrict__ x, const float* __restrict__ W1, const float* __restrict__ W2,
    const int* __restrict__ counts, const int* __restrict__ lists, const float* __restrict__ pw,
    float* __restrict__ out)
{
    int e    = blockIdx.y;
    int tile = blockIdx.x;
    int cnt  = counts[e];
    int start = tile * BMF;
    if (start >= cnt) return;

    __shared__ float xs[BMF][DM];
    __shared__ float hs[BMF][BFF];
    __shared__ int   toks[BMF];
    __shared__ float wgt[BMF];

    int tid = threadIdx.x;
    int nm  = cnt - start; if (nm > BMF) nm = BMF;

    if (tid < BMF) {
        if (tid < nm) {
            int p = lists[e * T_TOK + start + tid];
            toks[tid] = p >> 1;
            wgt[tid]  = pw[p];
        } else { toks[tid] = -1; wgt[tid] = 0.f; }
    }
    __syncthreads();
    for (int m = 0; m < BMF; ++m) {
        int t = toks[m];
        const float* xr = (t >= 0) ? (x + (size_t)t * DM) : nullptr;
        for (int i = tid; i < DM; i += 256) xs[m][i] = (t >= 0) ? xr[i] : 0.f;
    }
    __syncthreads();

    const float* W1e = W1 + (size_t)e * DM * DF;
    const float* W2e = W2 + (size_t)e * DF * DM;
    float acc[BMF][4];
#pragma unroll
    for (int m = 0; m < BMF; ++m)
#pragma unroll
        for (int c = 0; c < 4; ++c) acc[m][c] = 0.f;

    for (int fc = 0; fc < DF; fc += BFF) {
        float hacc[BMF];
#pragma unroll
        for (int m = 0; m < BMF; ++m) hacc[m] = 0.f;
        const float* w1col = W1e + fc + tid;
#pragma unroll 4
        for (int i = 0; i < DM; ++i) {
            float w1v = w1col[(size_t)i * DF];
#pragma unroll
            for (int m = 0; m < BMF; ++m) hacc[m] += xs[m][i] * w1v;
        }
        __syncthreads();
#pragma unroll
        for (int m = 0; m < BMF; ++m) {
            float v = hacc[m];
            hs[m][tid] = v / (1.f + __expf(-v));
        }
        __syncthreads();
        const float* w2base = W2e + (size_t)fc * DM + tid * 4;
        for (int f = 0; f < BFF; ++f) {
            float4 w2v = *reinterpret_cast<const float4*>(w2base + (size_t)f * DM);
#pragma unroll
            for (int m = 0; m < BMF; ++m) {
                float h = hs[m][f];
                acc[m][0] += h * w2v.x; acc[m][1] += h * w2v.y;
                acc[m][2] += h * w2v.z; acc[m][3] += h * w2v.w;
            }
        }
        __syncthreads();
    }
    int c0 = tid * 4;
#pragma unroll
    for (int m = 0; m < BMF; ++m) {
        int t = toks[m];
        if (t < 0) continue;
        float w = wgt[m];
        float* op = out + (size_t)t * DM + c0;
        atomicAdd(op + 0, w * acc[m][0]);
        atomicAdd(op + 1, w * acc[m][1]);
        atomicAdd(op + 2, w * acc[m][2]);
        atomicAdd(op + 3, w * acc[m][3]);
    }
}

// ================= launch =================
extern "C" void kernel_launch(void* const* d_in, const int* in_sizes, int n_in,
                              void* d_out, int out_size, void* d_ws, size_t ws_size,
                              hipStream_t stream)
{
    const float* x  = (const float*)d_in[0];
    const float* Wg = (const float*)d_in[1];
    const float* W1 = (const float*)d_in[2];
    const float* W2 = (const float*)d_in[3];
    float* out = (float*)d_out;

    char* ws = (char*)d_ws;
    int*      counts  = (int*)(ws + 0);
    int*      offsets = (int*)(ws + 64);
    int*      ntp     = (int*)(ws + 128);
    unsigned* table   = (unsigned*)(ws + 256);        // 72*4 = 288 B
    int*      lists   = (int*)(ws + 2048);            // 256 KB
    float*    pw      = (float*)(ws + 2048 + 262144); // 64 KB

    const size_t o_xb  = 524288;
    const size_t sz_xb = (size_t)T_TOK * DM * 2;              // 16 MB
    const size_t o_w1t = o_xb + sz_xb;
    const size_t sz_w  = (size_t)NE * DM * DF * 2;            // 64 MB each
    const size_t o_w2t = o_w1t + sz_w;
    const size_t o_h   = o_w2t + sz_w;
    const size_t sz_h  = (size_t)(2 * T_TOK) * DF * 2;        // 134 MB
    const size_t NEEDED = o_h + sz_h;

    bool fast = (ws_size >= NEEDED);
    unsigned short* xb = fast ? (unsigned short*)(ws + o_xb) : nullptr;

    hipMemsetAsync(counts, 0, 64, stream);
    route_kernel<<<T_TOK / 4, 256, 0, stream>>>(x, Wg, counts, lists, pw, xb);

    if (fast) {
        unsigned short* w1t = (unsigned short*)(ws + o_w1t);
        unsigned short* w2t = (unsigned short*)(ws + o_w2t);
        unsigned short* H   = (unsigned short*)(ws + o_h);

        hipMemsetAsync(d_out, 0, (size_t)out_size * sizeof(float), stream);
        offsets_kernel<<<1, 64, 0, stream>>>(counts, offsets, table, ntp);
        {
            dim3 g(DM / 64, DF / 64, NE);
            transpose_conv_kernel<DM, DF><<<g, 256, 0, stream>>>(W1, w1t);
        }
        {
            dim3 g(DF / 64, DM / 64, NE);
            transpose_conv_kernel<DF, DM><<<g, 256, 0, stream>>>(W2, w2t);
        }
        // G1: [cnt x 1024] @ W1t -> silu -> H (bf16), 256x128 tiles
        moe_gemm11<DF, DM, 1, true><<<dim3(MAXT * 32), 512, 0, stream>>>(
            xb, w1t, counts, offsets, lists, table, ntp, pw, H, nullptr);
        // G2: H @ W2t -> gated atomic-add into out, 256x128 tiles, split-K 2
        moe_gemm11<DM, DF, 2, false><<<dim3(MAXT * 16), 512, 0, stream>>>(
            H, w2t, counts, offsets, lists, table, ntp, pw, nullptr, out);
    } else {
        hipMemsetAsync(d_out, 0, (size_t)out_size * sizeof(float), stream);
        dim3 grid(T_TOK / BMF, NE);
        expert_gemm_f32<<<grid, 256, 0, stream>>>(x, W1, W2, counts, lists, pw, out);
    }
}